// Round 16
// baseline (187.215 us; speedup 1.0000x reference)
//
#include <hip/hip_runtime.h>

// N=1536 T=20 H=64 E=16 M=128
// Qf[j,k] (16x16-MFMA-frag-tile layout), P[j,k]: fp16 in d_ws; W2f:
// pre-fragmented W2 (16KB). out[i] = max_j relu( relu(Q[j]-P[i]) @ W2 + b2 )
//
// R17 RESUBMIT (round died to container infra -- third infra failure this
// session, R6/R11 precedent: unchanged resubmit succeeded; kernel audit
// found no hang/fault candidates: no barriers, no LDS, no asm).
//
// Theory: the unified occupancy model. MFMA blocks its wave ~77-80cy (vs
// ~19cy pipe occupancy) => need ~4 independently-issuing waves/SIMD; we
// always had 2 => 45% duty everywhere (matches all 15 rounds + ubench's
// 8-wave requirement). The two prerequisites were never simultaneous:
//   regs <= 128 unified (4-wave granule, m69)  -- R11 had it, 1-wave WGs
//   big workgroups (SPI packs ~5 tiny WGs/CU)  -- R12 had it, 160 regs
// R17 = R8's lean NI=1 wave (measured 64 VGPR + 16 AGPR = 80 unified)
// packaged 8 INDEPENDENT waves per 512-thr WG (no LDS, no barriers).
// launch_bounds(512,4): 4 waves/EU, cap 128 >= live ~80 (R5-safe).
// Waves in a WG: consecutive i, same js -> same Q tile stream (L1 share).
// Grid 768 WGs = 24 waves/CU supplied >= 16 resident. Scaffold: R13 byte
// addressing + 2x-unrolled ping-pong + setprio + deferred b2/relu.

#define NN 1536
#define HH 64
#define EE 16
#define MM 128
#define TT 20

#define JSPLIT 4
#define NTILE (96 / JSPLIT)   // 24 j-tiles of 16 per wave
#define BW 8                  // independent waves per block (512 thr)

typedef _Float16 half8 __attribute__((ext_vector_type(8)));
typedef float f32x4 __attribute__((ext_vector_type(4)));

// grid NN, block 128. Computes Qf (16x16 frag-tile layout), P, W2f,
// zero-inits out. (verified R6-R16)
__global__ __launch_bounds__(128) void precompute_kernel(
    const float* __restrict__ hidden, const float* __restrict__ gt,
    const float* __restrict__ We, const float* __restrict__ be,
    const float* __restrict__ W1, const float* __restrict__ b1,
    const float* __restrict__ W2,
    _Float16* __restrict__ Qf, _Float16* __restrict__ P,
    _Float16* __restrict__ W2f, float* __restrict__ out)
{
  const int j = blockIdx.x;
  const int m = threadIdx.x;
  const float* hrow = hidden + j * HH;
  float a0 = 0.f, a1 = 0.f;
  #pragma unroll 8
  for (int h = 0; h < HH; h += 2) {
    a0 = fmaf(hrow[h],     W1[h * MM + m],       a0);
    a1 = fmaf(hrow[h + 1], W1[(h + 1) * MM + m], a1);
  }
  const float a = a0 + a1;
  float ve0 = 0.f, ve1 = 0.f, cm = b1[m];
  #pragma unroll
  for (int e = 0; e < EE; ++e) {
    float w1e = W1[(HH + e) * MM + m];
    ve0 = fmaf(We[e], w1e, ve0);       // We[0][e]
    ve1 = fmaf(We[EE + e], w1e, ve1);  // We[1][e]
    cm  = fmaf(be[e], w1e, cm);
  }
  const float e0 = gt[j * (2 * TT) + 2 * (TT - 1)];
  const float e1 = gt[j * (2 * TT) + 2 * (TT - 1) + 1];
  const float p = fmaf(e0, ve0, e1 * ve1);
  P[j * MM + m] = (_Float16)p;

  const int jt = j >> 4;
  const int ks = m >> 5;
  const int ln = ((m >> 3) & 3) * 16 + (j & 15);
  const int jj = m & 7;
  Qf[(((jt * 4) + ks) * 64 + ln) * 8 + jj] = (_Float16)(a + p + cm);

  if (m < HH) out[j * HH + m] = 0.f;

  // blocks 0..7: pre-fragment W2 -> W2f (verified R8-R16).
  if (j < 8) {
    const int u = j * 128 + m;          // 0..1023
    const int ct = u >> 8;
    const int ksx = (u >> 6) & 3;
    const int l = u & 63;
    half8 w;
    #pragma unroll
    for (int t = 0; t < 8; ++t)
      w[t] = (_Float16)W2[(ksx * 32 + (l >> 4) * 8 + t) * HH + ct * 16 + (l & 15)];
    *(half8*)(W2f + (size_t)u * 8) = w;
  }
}

// grid NN*JSPLIT/BW = 768, block 512 (8 INDEPENDENT waves). Wave gid =
// bid*8+wid: i = gid%NN, js = gid/NN (1536%8==0 => all 8 waves same js).
// Per wave: NI=1, CT=4 (each s feeds 4 MFMA), 16 MFMA/tile, ping-pong.
__global__ __launch_bounds__(512, 4) void pairmlp_max_kernel(
    const _Float16* __restrict__ Qf, const _Float16* __restrict__ P,
    const _Float16* __restrict__ W2f, const float* __restrict__ b2,
    float* __restrict__ out)
{
  const int lane = threadIdx.x & 63;
  const int wid  = threadIdx.x >> 6;
  const int quad = lane >> 4;
  const int lcol = lane & 15;
  const int gid = blockIdx.x * BW + wid;
  const int i  = gid % NN;    // consecutive waves in a WG: consecutive i,
  const int js = gid / NN;    // same js -> identical Q tile stream (L1 share)

  // B fragments from pre-fragmented W2f: 16 coalesced 16B loads
  half8 bfrag[4][4];
  {
    const half8* wf = (const half8*)W2f + lane;
    #pragma unroll
    for (int ct = 0; ct < 4; ++ct)
      #pragma unroll
      for (int ks = 0; ks < 4; ++ks)
        bfrag[ct][ks] = wf[(ct * 4 + ks) * 64];
  }

  // P fragment for this wave's single i
  half8 pv[4];
  {
    const _Float16* prow = P + i * MM + quad * 8;
    #pragma unroll
    for (int ks = 0; ks < 4; ++ks)
      pv[ks] = *(const half8*)(prow + ks * 32);
  }

  float rmax[4];
  #pragma unroll
  for (int ct = 0; ct < 4; ++ct) rmax[ct] = -3.0e38f;

  // byte base: tile jt at jt*4096, ks at +1024*ks, lane at +16*lane
  const char* qp = (const char*)Qf + (size_t)(js * NTILE) * 4096 + lane * 16;

  const half8 hz = 0;
  const f32x4 fz = {0.f, 0.f, 0.f, 0.f};

  // compute one 16-j tile held in qt[4] against this wave's i
  auto compute_tile = [&](const half8* qt) {
    f32x4 acc[4];
    __builtin_amdgcn_s_setprio(1);
    {
      half8 s = qt[0] - pv[0];
      s = __builtin_elementwise_max(s, hz);
      #pragma unroll
      for (int ct = 0; ct < 4; ++ct)
        acc[ct] = __builtin_amdgcn_mfma_f32_16x16x32_f16(s, bfrag[ct][0], fz, 0, 0, 0);
    }
    #pragma unroll
    for (int ks = 1; ks < 4; ++ks) {
      half8 s = qt[ks] - pv[ks];
      s = __builtin_elementwise_max(s, hz);
      #pragma unroll
      for (int ct = 0; ct < 4; ++ct)
        acc[ct] = __builtin_amdgcn_mfma_f32_16x16x32_f16(s, bfrag[ct][ks], acc[ct], 0, 0, 0);
    }
    __builtin_amdgcn_s_setprio(0);
    // C/D: col=lcol+ct*16, row(j)=quad*4+reg. Raw max; +b2/relu deferred.
    #pragma unroll
    for (int ct = 0; ct < 4; ++ct) {
      const float t3 = fmaxf(fmaxf(acc[ct][0], acc[ct][1]), acc[ct][2]);
      rmax[ct] = fmaxf(fmaxf(t3, acc[ct][3]), rmax[ct]);
    }
  };

  half8 qc[4], qn[4];

  // prime qc from tile 0
  #pragma unroll
  for (int ks = 0; ks < 4; ++ks)
    qc[ks] = *(const half8*)(qp + ks * 1024);

  // 2x-unrolled ping-pong: no qc<-qn register copies
  for (int t = 0; t < NTILE; t += 2) {
    // prefetch tile t+1 (imm offsets off qp+4096)
    #pragma unroll
    for (int ks = 0; ks < 4; ++ks)
      qn[ks] = *(const half8*)(qp + 4096 + ks * 1024);
    compute_tile(qc);  // tile t

    // prefetch tile t+2 (dummy tile-0 reload on last pair; unused)
    const char* q2 = (t + 2 < NTILE) ? (qp + 8192)
                                     : ((const char*)Qf + (size_t)(js * NTILE) * 4096 + lane * 16);
    #pragma unroll
    for (int ks = 0; ks < 4; ++ks)
      qc[ks] = *(const half8*)(q2 + ks * 1024);
    compute_tile(qn);  // tile t+1

    qp += 8192;
  }

  // combine quad-groups (different j rows, same col), then b2+relu+atomic.
  #pragma unroll
  for (int ct = 0; ct < 4; ++ct) {
    float v = rmax[ct];
    v = fmaxf(v, __shfl_xor(v, 16, 64));
    v = fmaxf(v, __shfl_xor(v, 32, 64));
    v = fmaxf(v + b2[ct * 16 + lcol], 0.f);
    if (quad == 0)
      atomicMax((unsigned*)(out + i * HH + ct * 16 + lcol), __float_as_uint(v));
  }
}

extern "C" void kernel_launch(void* const* d_in, const int* in_sizes, int n_in,
                              void* d_out, int out_size, void* d_ws, size_t ws_size,
                              hipStream_t stream) {
  const float* hidden = (const float*)d_in[0];
  const float* gt     = (const float*)d_in[1];
  const float* We     = (const float*)d_in[2];
  const float* be     = (const float*)d_in[3];
  const float* W1     = (const float*)d_in[4];
  const float* b1     = (const float*)d_in[5];
  const float* W2     = (const float*)d_in[6];
  const float* b2     = (const float*)d_in[7];
  float* out = (float*)d_out;

  _Float16* Qf  = (_Float16*)d_ws;     // NN*MM fp16 (384KB), frag-tile layout
  _Float16* Ph  = Qf + NN * MM;        // NN*MM fp16 (384KB)
  _Float16* W2f = Ph + NN * MM;        // 4*4*64*8 fp16 (16KB), frag layout

  precompute_kernel<<<NN, 128, 0, stream>>>(hidden, gt, We, be, W1, b1, W2, Qf, Ph, W2f, out);
  pairmlp_max_kernel<<<(NN * JSPLIT) / BW, 512, 0, stream>>>(Qf, Ph, W2f, b2, out);
}

// Round 17
// 136.882 us; speedup vs baseline: 1.3677x; 1.3677x over previous
//
#include <hip/hip_runtime.h>

// N=1536 T=20 H=64 E=16 M=128
// Qf[j,k] (16x16-MFMA-frag-tile layout), P[j,k]: fp16 in d_ws; W2f:
// pre-fragmented W2 (16KB). out[i] = max_j relu( relu(Q[j]-P[i]) @ W2 + b2 )
//
// R18: the only measured-<=128 wave (R11: NI=2, 92 VGPR + 32 AGPR = 124
// unified) packaged in 4-independent-wave 256-thr WGs (R12 shape). R17
// proved both halves of the model: big-WG+low-reg DID raise residency
// (occ 16->35%) but its NI=1 live set (~145) spilled under the 128 cap
// (FETCH 50MB/WRITE 103MB). R11's NI=2 is the structure that measured
// 124 <= 128. launch_bounds(256,3): cap 170 -- allocator keeps its
// measured 124 (no squeeze, R5), runtime packs 4 waves/SIMD by granule.
// Waves in a WG: consecutive i-pairs, same js -> shared Q stream (L1).
// JSPLIT=6: 4608 waves = 18/CU supplied >= 16 resident. R13's byte
// addressing + wid-parity half-run stagger (reg-saving, proven).
// Tripwire: VGPR >110 or WRITE >=10MB = spill -> revert R13.

#define NN 1536
#define HH 64
#define EE 16
#define MM 128
#define TT 20

#define NI 2
#define NIGRP (NN / NI)       // 768 i-groups
#define JSPLIT 6
#define NTILE (96 / JSPLIT)   // 16 j-tiles of 16 per wave
#define HTILE (NTILE / 2)     // 8 per half-run
#define BW 4                  // independent waves per block (256 thr)

typedef _Float16 half8 __attribute__((ext_vector_type(8)));
typedef float f32x4 __attribute__((ext_vector_type(4)));

// grid NN, block 128. Computes Qf (16x16 frag-tile layout), P, W2f,
// zero-inits out. (verified R6-R17)
__global__ __launch_bounds__(128) void precompute_kernel(
    const float* __restrict__ hidden, const float* __restrict__ gt,
    const float* __restrict__ We, const float* __restrict__ be,
    const float* __restrict__ W1, const float* __restrict__ b1,
    const float* __restrict__ W2,
    _Float16* __restrict__ Qf, _Float16* __restrict__ P,
    _Float16* __restrict__ W2f, float* __restrict__ out)
{
  const int j = blockIdx.x;
  const int m = threadIdx.x;
  const float* hrow = hidden + j * HH;
  float a0 = 0.f, a1 = 0.f;
  #pragma unroll 8
  for (int h = 0; h < HH; h += 2) {
    a0 = fmaf(hrow[h],     W1[h * MM + m],       a0);
    a1 = fmaf(hrow[h + 1], W1[(h + 1) * MM + m], a1);
  }
  const float a = a0 + a1;
  float ve0 = 0.f, ve1 = 0.f, cm = b1[m];
  #pragma unroll
  for (int e = 0; e < EE; ++e) {
    float w1e = W1[(HH + e) * MM + m];
    ve0 = fmaf(We[e], w1e, ve0);       // We[0][e]
    ve1 = fmaf(We[EE + e], w1e, ve1);  // We[1][e]
    cm  = fmaf(be[e], w1e, cm);
  }
  const float e0 = gt[j * (2 * TT) + 2 * (TT - 1)];
  const float e1 = gt[j * (2 * TT) + 2 * (TT - 1) + 1];
  const float p = fmaf(e0, ve0, e1 * ve1);
  P[j * MM + m] = (_Float16)p;

  const int jt = j >> 4;
  const int ks = m >> 5;
  const int ln = ((m >> 3) & 3) * 16 + (j & 15);
  const int jj = m & 7;
  Qf[(((jt * 4) + ks) * 64 + ln) * 8 + jj] = (_Float16)(a + p + cm);

  if (m < HH) out[j * HH + m] = 0.f;

  // blocks 0..7: pre-fragment W2 -> W2f (verified R8-R17).
  if (j < 8) {
    const int u = j * 128 + m;          // 0..1023
    const int ct = u >> 8;
    const int ksx = (u >> 6) & 3;
    const int l = u & 63;
    half8 w;
    #pragma unroll
    for (int t = 0; t < 8; ++t)
      w[t] = (_Float16)W2[(ksx * 32 + (l >> 4) * 8 + t) * HH + ct * 16 + (l & 15)];
    *(half8*)(W2f + (size_t)u * 8) = w;
  }
}

// grid NIGRP*JSPLIT/BW = 1152, block 256 (4 INDEPENDENT waves, no barriers,
// no LDS). Wave gid = bid*4+wid: i0 = (gid%NIGRP)*2, js = gid/NIGRP
// (768%4==0 => all 4 waves in a WG share js; consecutive i-pairs).
__global__ __launch_bounds__(256, 3) void pairmlp_max_kernel(
    const _Float16* __restrict__ Qf, const _Float16* __restrict__ P,
    const _Float16* __restrict__ W2f, const float* __restrict__ b2,
    float* __restrict__ out)
{
  const int lane = threadIdx.x & 63;
  const int wid  = threadIdx.x >> 6;
  const int quad = lane >> 4;
  const int lcol = lane & 15;
  const int gid = blockIdx.x * BW + wid;
  const int ig = gid % NIGRP;
  const int js = gid / NIGRP;
  const int i0 = ig * NI;
  const int par = wid & 1;            // intra-WG anti-phase stagger

  // B fragments from pre-fragmented W2f: 16 coalesced 16B loads
  half8 bfrag[4][4];
  {
    const half8* wf = (const half8*)W2f + lane;
    #pragma unroll
    for (int ct = 0; ct < 4; ++ct)
      #pragma unroll
      for (int ks = 0; ks < 4; ++ks)
        bfrag[ct][ks] = wf[(ct * 4 + ks) * 64];
  }

  // P fragments for NI i's
  half8 pv[NI][4];
  #pragma unroll
  for (int ii = 0; ii < NI; ++ii) {
    const _Float16* prow = P + (i0 + ii) * MM + quad * 8;
    #pragma unroll
    for (int ks = 0; ks < 4; ++ks)
      pv[ii][ks] = *(const half8*)(prow + ks * 32);
  }

  float b2v[4];
  #pragma unroll
  for (int ct = 0; ct < 4; ++ct) b2v[ct] = b2[ct * 16 + lcol];

  float rmax[NI][4];
  #pragma unroll
  for (int ii = 0; ii < NI; ++ii)
    #pragma unroll
    for (int ct = 0; ct < 4; ++ct) rmax[ii][ct] = -3.0e38f;

  // byte base: tile jt at jt*4096, ks at +1024*ks, lane at +16*lane
  const char* qbytes = (const char*)Qf + (size_t)(js * NTILE) * 4096 + lane * 16;

  const half8 hz = 0;
  const f32x4 fz = {0.f, 0.f, 0.f, 0.f};

  // compute one 16-j tile held in qt[4] against both i's
  auto compute_tile = [&](const half8* qt) {
    f32x4 acc[NI][4];
    #pragma unroll
    for (int ks = 0; ks < 4; ++ks) {
      __builtin_amdgcn_s_setprio(1);
      #pragma unroll
      for (int ii = 0; ii < NI; ++ii) {
        half8 s = qt[ks] - pv[ii][ks];
        s = __builtin_elementwise_max(s, hz);
        #pragma unroll
        for (int ct = 0; ct < 4; ++ct) {
          if (ks == 0)
            acc[ii][ct] = __builtin_amdgcn_mfma_f32_16x16x32_f16(
                s, bfrag[ct][0], fz, 0, 0, 0);
          else
            acc[ii][ct] = __builtin_amdgcn_mfma_f32_16x16x32_f16(
                s, bfrag[ct][ks], acc[ii][ct], 0, 0, 0);
        }
      }
      __builtin_amdgcn_s_setprio(0);
    }
    // C/D: col=lcol+ct*16, row(j)=quad*4+reg. Raw max; +b2/relu deferred.
    #pragma unroll
    for (int ii = 0; ii < NI; ++ii)
      #pragma unroll
      for (int ct = 0; ct < 4; ++ct) {
        const float t3 = fmaxf(fmaxf(acc[ii][ct][0], acc[ii][ct][1]), acc[ii][ct][2]);
        rmax[ii][ct] = fmaxf(fmaxf(t3, acc[ii][ct][3]), rmax[ii][ct]);
      }
  };

  half8 qc[4], qn[4];

  // two half-runs of HTILE tiles; order swapped by wid parity (anti-phase)
  for (int h = 0; h < 2; ++h) {
    const char* runb = qbytes + (((h ^ par) != 0) ? HTILE * 4096 : 0);
    const char* qp = runb;

    // prime qc from first tile of this run
    #pragma unroll
    for (int ks = 0; ks < 4; ++ks)
      qc[ks] = *(const half8*)(qp + ks * 1024);

    for (int t = 0; t < HTILE; t += 2) {
      // prefetch tile t+1 (imm offsets off qp+4096)
      #pragma unroll
      for (int ks = 0; ks < 4; ++ks)
        qn[ks] = *(const half8*)(qp + 4096 + ks * 1024);
      compute_tile(qc);  // tile t

      // prefetch tile t+2 (dummy run-start on last pair; unused)
      const char* q2 = (t + 2 < HTILE) ? (qp + 8192) : runb;
      #pragma unroll
      for (int ks = 0; ks < 4; ++ks)
        qc[ks] = *(const half8*)(q2 + ks * 1024);
      compute_tile(qn);  // tile t+1

      qp += 8192;
    }
  }

  // combine quad-groups (different j rows, same col), then atomic max.
  #pragma unroll
  for (int ii = 0; ii < NI; ++ii)
    #pragma unroll
    for (int ct = 0; ct < 4; ++ct) {
      float v = rmax[ii][ct];
      v = fmaxf(v, __shfl_xor(v, 16, 64));
      v = fmaxf(v, __shfl_xor(v, 32, 64));
      v = fmaxf(v + b2v[ct], 0.f);
      if (quad == 0)
        atomicMax((unsigned*)(out + (i0 + ii) * HH + ct * 16 + lcol), __float_as_uint(v));
    }
}

extern "C" void kernel_launch(void* const* d_in, const int* in_sizes, int n_in,
                              void* d_out, int out_size, void* d_ws, size_t ws_size,
                              hipStream_t stream) {
  const float* hidden = (const float*)d_in[0];
  const float* gt     = (const float*)d_in[1];
  const float* We     = (const float*)d_in[2];
  const float* be     = (const float*)d_in[3];
  const float* W1     = (const float*)d_in[4];
  const float* b1     = (const float*)d_in[5];
  const float* W2     = (const float*)d_in[6];
  const float* b2     = (const float*)d_in[7];
  float* out = (float*)d_out;

  _Float16* Qf  = (_Float16*)d_ws;     // NN*MM fp16 (384KB), frag-tile layout
  _Float16* Ph  = Qf + NN * MM;        // NN*MM fp16 (384KB)
  _Float16* W2f = Ph + NN * MM;        // 4*4*64*8 fp16 (16KB), frag layout

  precompute_kernel<<<NN, 128, 0, stream>>>(hidden, gt, We, be, W1, b1, W2, Qf, Ph, W2f, out);
  pairmlp_max_kernel<<<(NIGRP * JSPLIT) / BW, 256, 0, stream>>>(Qf, Ph, W2f, b2, out);
}

// Round 18
// 108.742 us; speedup vs baseline: 1.7217x; 1.2588x over previous
//
#include <hip/hip_runtime.h>

// N=1536 T=20 H=64 E=16 M=128
// Qf[j,k] (16x16-MFMA-frag-tile layout), P[j,k]: fp16 in d_ws; W2f:
// pre-fragmented W2 (16KB). out[i] = max_j relu( relu(Q[j]-P[i]) @ W2 + b2 )
//
// R19 = R18 with the allocator squeeze removed: launch_bounds(256,2).
// Evidence: min-waves>=3 ALWAYS spills (R5/R17/R18: WRITE 33/103/42MB);
// big-WG+fits-128 raises residency (R17: occ 35%, only run past 25%);
// (256,2) packaging leaves codegen untouched (R12: VGPR 112 = R9's).
// The NI=2 wave measured 92 VGPR + 32 AGPR = 124 unified <= 128 HONESTLY
// (R11, relaxed cap) -> 4 waves/SIMD by the 64/128/256 granule (m69),
// no coercion. First config satisfying all three prerequisites:
// honest fit + <=128 + 4-wave WG shape.
// Controls: VGPR must read ~92 (codegen unchanged); WRITE ~2.3MB (no
// spill). Falsifier: occ pinned ~16% with both controls clean -> model
// dead, revert R13 and declare floor.

#define NN 1536
#define HH 64
#define EE 16
#define MM 128
#define TT 20

#define NI 2
#define NIGRP (NN / NI)       // 768 i-groups
#define JSPLIT 6
#define NTILE (96 / JSPLIT)   // 16 j-tiles of 16 per wave
#define HTILE (NTILE / 2)     // 8 per half-run
#define BW 4                  // independent waves per block (256 thr)

typedef _Float16 half8 __attribute__((ext_vector_type(8)));
typedef float f32x4 __attribute__((ext_vector_type(4)));

// grid NN, block 128. Computes Qf (16x16 frag-tile layout), P, W2f,
// zero-inits out. (verified R6-R18)
__global__ __launch_bounds__(128) void precompute_kernel(
    const float* __restrict__ hidden, const float* __restrict__ gt,
    const float* __restrict__ We, const float* __restrict__ be,
    const float* __restrict__ W1, const float* __restrict__ b1,
    const float* __restrict__ W2,
    _Float16* __restrict__ Qf, _Float16* __restrict__ P,
    _Float16* __restrict__ W2f, float* __restrict__ out)
{
  const int j = blockIdx.x;
  const int m = threadIdx.x;
  const float* hrow = hidden + j * HH;
  float a0 = 0.f, a1 = 0.f;
  #pragma unroll 8
  for (int h = 0; h < HH; h += 2) {
    a0 = fmaf(hrow[h],     W1[h * MM + m],       a0);
    a1 = fmaf(hrow[h + 1], W1[(h + 1) * MM + m], a1);
  }
  const float a = a0 + a1;
  float ve0 = 0.f, ve1 = 0.f, cm = b1[m];
  #pragma unroll
  for (int e = 0; e < EE; ++e) {
    float w1e = W1[(HH + e) * MM + m];
    ve0 = fmaf(We[e], w1e, ve0);       // We[0][e]
    ve1 = fmaf(We[EE + e], w1e, ve1);  // We[1][e]
    cm  = fmaf(be[e], w1e, cm);
  }
  const float e0 = gt[j * (2 * TT) + 2 * (TT - 1)];
  const float e1 = gt[j * (2 * TT) + 2 * (TT - 1) + 1];
  const float p = fmaf(e0, ve0, e1 * ve1);
  P[j * MM + m] = (_Float16)p;

  const int jt = j >> 4;
  const int ks = m >> 5;
  const int ln = ((m >> 3) & 3) * 16 + (j & 15);
  const int jj = m & 7;
  Qf[(((jt * 4) + ks) * 64 + ln) * 8 + jj] = (_Float16)(a + p + cm);

  if (m < HH) out[j * HH + m] = 0.f;

  // blocks 0..7: pre-fragment W2 -> W2f (verified R8-R18).
  if (j < 8) {
    const int u = j * 128 + m;          // 0..1023
    const int ct = u >> 8;
    const int ksx = (u >> 6) & 3;
    const int l = u & 63;
    half8 w;
    #pragma unroll
    for (int t = 0; t < 8; ++t)
      w[t] = (_Float16)W2[(ksx * 32 + (l >> 4) * 8 + t) * HH + ct * 16 + (l & 15)];
    *(half8*)(W2f + (size_t)u * 8) = w;
  }
}

// grid NIGRP*JSPLIT/BW = 1152, block 256 (4 INDEPENDENT waves, no barriers,
// no LDS). Wave gid = bid*4+wid: i0 = (gid%NIGRP)*2, js = gid/NIGRP
// (768%4==0 => all 4 waves in a WG share js; consecutive i-pairs).
__global__ __launch_bounds__(256, 2) void pairmlp_max_kernel(
    const _Float16* __restrict__ Qf, const _Float16* __restrict__ P,
    const _Float16* __restrict__ W2f, const float* __restrict__ b2,
    float* __restrict__ out)
{
  const int lane = threadIdx.x & 63;
  const int wid  = threadIdx.x >> 6;
  const int quad = lane >> 4;
  const int lcol = lane & 15;
  const int gid = blockIdx.x * BW + wid;
  const int ig = gid % NIGRP;
  const int js = gid / NIGRP;
  const int i0 = ig * NI;
  const int par = wid & 1;            // intra-WG anti-phase stagger

  // B fragments from pre-fragmented W2f: 16 coalesced 16B loads
  half8 bfrag[4][4];
  {
    const half8* wf = (const half8*)W2f + lane;
    #pragma unroll
    for (int ct = 0; ct < 4; ++ct)
      #pragma unroll
      for (int ks = 0; ks < 4; ++ks)
        bfrag[ct][ks] = wf[(ct * 4 + ks) * 64];
  }

  // P fragments for NI i's
  half8 pv[NI][4];
  #pragma unroll
  for (int ii = 0; ii < NI; ++ii) {
    const _Float16* prow = P + (i0 + ii) * MM + quad * 8;
    #pragma unroll
    for (int ks = 0; ks < 4; ++ks)
      pv[ii][ks] = *(const half8*)(prow + ks * 32);
  }

  float b2v[4];
  #pragma unroll
  for (int ct = 0; ct < 4; ++ct) b2v[ct] = b2[ct * 16 + lcol];

  float rmax[NI][4];
  #pragma unroll
  for (int ii = 0; ii < NI; ++ii)
    #pragma unroll
    for (int ct = 0; ct < 4; ++ct) rmax[ii][ct] = -3.0e38f;

  // byte base: tile jt at jt*4096, ks at +1024*ks, lane at +16*lane
  const char* qbytes = (const char*)Qf + (size_t)(js * NTILE) * 4096 + lane * 16;

  const half8 hz = 0;
  const f32x4 fz = {0.f, 0.f, 0.f, 0.f};

  // compute one 16-j tile held in qt[4] against both i's
  auto compute_tile = [&](const half8* qt) {
    f32x4 acc[NI][4];
    #pragma unroll
    for (int ks = 0; ks < 4; ++ks) {
      __builtin_amdgcn_s_setprio(1);
      #pragma unroll
      for (int ii = 0; ii < NI; ++ii) {
        half8 s = qt[ks] - pv[ii][ks];
        s = __builtin_elementwise_max(s, hz);
        #pragma unroll
        for (int ct = 0; ct < 4; ++ct) {
          if (ks == 0)
            acc[ii][ct] = __builtin_amdgcn_mfma_f32_16x16x32_f16(
                s, bfrag[ct][0], fz, 0, 0, 0);
          else
            acc[ii][ct] = __builtin_amdgcn_mfma_f32_16x16x32_f16(
                s, bfrag[ct][ks], acc[ii][ct], 0, 0, 0);
        }
      }
      __builtin_amdgcn_s_setprio(0);
    }
    // C/D: col=lcol+ct*16, row(j)=quad*4+reg. Raw max; +b2/relu deferred.
    #pragma unroll
    for (int ii = 0; ii < NI; ++ii)
      #pragma unroll
      for (int ct = 0; ct < 4; ++ct) {
        const float t3 = fmaxf(fmaxf(acc[ii][ct][0], acc[ii][ct][1]), acc[ii][ct][2]);
        rmax[ii][ct] = fmaxf(fmaxf(t3, acc[ii][ct][3]), rmax[ii][ct]);
      }
  };

  half8 qc[4], qn[4];

  // two half-runs of HTILE tiles; order swapped by wid parity (anti-phase)
  for (int h = 0; h < 2; ++h) {
    const char* runb = qbytes + (((h ^ par) != 0) ? HTILE * 4096 : 0);
    const char* qp = runb;

    // prime qc from first tile of this run
    #pragma unroll
    for (int ks = 0; ks < 4; ++ks)
      qc[ks] = *(const half8*)(qp + ks * 1024);

    for (int t = 0; t < HTILE; t += 2) {
      // prefetch tile t+1 (imm offsets off qp+4096)
      #pragma unroll
      for (int ks = 0; ks < 4; ++ks)
        qn[ks] = *(const half8*)(qp + 4096 + ks * 1024);
      compute_tile(qc);  // tile t

      // prefetch tile t+2 (dummy run-start on last pair; unused)
      const char* q2 = (t + 2 < HTILE) ? (qp + 8192) : runb;
      #pragma unroll
      for (int ks = 0; ks < 4; ++ks)
        qc[ks] = *(const half8*)(q2 + ks * 1024);
      compute_tile(qn);  // tile t+1

      qp += 8192;
    }
  }

  // combine quad-groups (different j rows, same col), then atomic max.
  #pragma unroll
  for (int ii = 0; ii < NI; ++ii)
    #pragma unroll
    for (int ct = 0; ct < 4; ++ct) {
      float v = rmax[ii][ct];
      v = fmaxf(v, __shfl_xor(v, 16, 64));
      v = fmaxf(v, __shfl_xor(v, 32, 64));
      v = fmaxf(v + b2v[ct], 0.f);
      if (quad == 0)
        atomicMax((unsigned*)(out + (i0 + ii) * HH + ct * 16 + lcol), __float_as_uint(v));
    }
}

extern "C" void kernel_launch(void* const* d_in, const int* in_sizes, int n_in,
                              void* d_out, int out_size, void* d_ws, size_t ws_size,
                              hipStream_t stream) {
  const float* hidden = (const float*)d_in[0];
  const float* gt     = (const float*)d_in[1];
  const float* We     = (const float*)d_in[2];
  const float* be     = (const float*)d_in[3];
  const float* W1     = (const float*)d_in[4];
  const float* b1     = (const float*)d_in[5];
  const float* W2     = (const float*)d_in[6];
  const float* b2     = (const float*)d_in[7];
  float* out = (float*)d_out;

  _Float16* Qf  = (_Float16*)d_ws;     // NN*MM fp16 (384KB), frag-tile layout
  _Float16* Ph  = Qf + NN * MM;        // NN*MM fp16 (384KB)
  _Float16* W2f = Ph + NN * MM;        // 4*4*64*8 fp16 (16KB), frag layout

  precompute_kernel<<<NN, 128, 0, stream>>>(hidden, gt, We, be, W1, b1, W2, Qf, Ph, W2f, out);
  pairmlp_max_kernel<<<(NIGRP * JSPLIT) / BW, 256, 0, stream>>>(Qf, Ph, W2f, b2, out);
}

// Round 19
// 103.432 us; speedup vs baseline: 1.8100x; 1.0513x over previous
//
#include <hip/hip_runtime.h>

// N=1536 T=20 H=64 E=16 M=128
// Qf[j,k] (MFMA-frag-tile layout), P[j,k]: fp16 in d_ws; W2f: pre-fragmented
// W2 (16KB fp16). out[i] = max_j relu( relu(Q[j]-P[i]) @ W2 + b2 )
//
// R20 FINAL = R13 exact revert (best measured: pairmlp 41.0us, total
// 102.6us). Session conclusion after 19 rounds:
//   MEASURED LAW: honest >=124-unified-reg waves get exactly 2 waves/SIMD
//   resident regardless of WG shape (R12/R19), supply (R10), or footprint
//   down to 124 (R11/R19); forcing smaller via launch_bounds>=3 spills
//   (R5/R17/R18: WRITE 33/103/42MB). Counted vmcnt = null (R14: compiler
//   waits already optimal). MFMA shape = null (R15). Drain pipelining
//   confounded-negative (R16).
//   FLOOR ARITHMETIC: 2.36M mfma_16x16x32 x ~19.4 SIMD-cyc / 1024 SIMD /
//   2.4GHz = 18.6us at 100% duty; 2 waves/SIMD x 19.4/77cy wave-blocking
//   latency ~ 50% max duty, minus A-frag VALU critical path -> ~35%
//   observed -> ~41us. R13 measured 41.0us = at-floor.
// This kernel: NI=3 density (48 MFMA / 4 loads -- the only lever that
// moved duration 54->43), W2f pre-frag, frag-layout coalesced Q loads,
// byte-pointer addressing (imm offsets), parity-staggered half-runs,
// 2x-unrolled ping-pong, setprio on MFMA clusters, deferred b2/relu,
// uint atomicMax epilogue. Grid 2048 1-wave blocks.

#define NN 1536
#define HH 64
#define EE 16
#define MM 128
#define TT 20

#define NI 3
#define NIGRP (NN / NI)       // 512 i-groups
#define JSPLIT 4
#define NTILE (96 / JSPLIT)   // 24 j-tiles of 16 per wave
#define HTILE (NTILE / 2)     // 12 per half-run

typedef _Float16 half8 __attribute__((ext_vector_type(8)));
typedef float f32x4 __attribute__((ext_vector_type(4)));

// grid NN, block 128. Computes Qf (frag-tile layout), P, W2f, zero-inits out.
// Qf entry: A[row=j&15][k=m] for tile jt=j>>4 lands where reading lane
// l finds halfs jj at ((jt*4+ks)*64+l)*8+jj with k = ks*32 + (l>>4)*8 + jj
//   ->  ks=m>>5, l=((m>>3)&3)*16+(j&15), jj=m&7.   (verified R6-R19)
__global__ __launch_bounds__(128) void precompute_kernel(
    const float* __restrict__ hidden, const float* __restrict__ gt,
    const float* __restrict__ We, const float* __restrict__ be,
    const float* __restrict__ W1, const float* __restrict__ b1,
    const float* __restrict__ W2,
    _Float16* __restrict__ Qf, _Float16* __restrict__ P,
    _Float16* __restrict__ W2f, float* __restrict__ out)
{
  const int j = blockIdx.x;
  const int m = threadIdx.x;
  const float* hrow = hidden + j * HH;
  float a0 = 0.f, a1 = 0.f;
  #pragma unroll 8
  for (int h = 0; h < HH; h += 2) {
    a0 = fmaf(hrow[h],     W1[h * MM + m],       a0);
    a1 = fmaf(hrow[h + 1], W1[(h + 1) * MM + m], a1);
  }
  const float a = a0 + a1;
  float ve0 = 0.f, ve1 = 0.f, cm = b1[m];
  #pragma unroll
  for (int e = 0; e < EE; ++e) {
    float w1e = W1[(HH + e) * MM + m];
    ve0 = fmaf(We[e], w1e, ve0);       // We[0][e]
    ve1 = fmaf(We[EE + e], w1e, ve1);  // We[1][e]
    cm  = fmaf(be[e], w1e, cm);
  }
  const float e0 = gt[j * (2 * TT) + 2 * (TT - 1)];
  const float e1 = gt[j * (2 * TT) + 2 * (TT - 1) + 1];
  const float p = fmaf(e0, ve0, e1 * ve1);
  P[j * MM + m] = (_Float16)p;

  const int jt = j >> 4;
  const int ks = m >> 5;
  const int ln = ((m >> 3) & 3) * 16 + (j & 15);
  const int jj = m & 7;
  Qf[(((jt * 4) + ks) * 64 + ln) * 8 + jj] = (_Float16)(a + p + cm);

  if (m < HH) out[j * HH + m] = 0.f;

  // blocks 0..7: pre-fragment W2 -> W2f (verified R8-R19).
  // unit u = ct*256 + ksx*64 + l holds halfs jj with
  // W2f[u*8+jj] = (fp16) W2[(ksx*32 + (l>>4)*8 + jj)*HH + ct*16 + (l&15)]
  if (j < 8) {
    const int u = j * 128 + m;          // 0..1023
    const int ct = u >> 8;
    const int ksx = (u >> 6) & 3;
    const int l = u & 63;
    half8 w;
    #pragma unroll
    for (int t = 0; t < 8; ++t)
      w[t] = (_Float16)W2[(ksx * 32 + (l >> 4) * 8 + t) * HH + ct * 16 + (l & 15)];
    *(half8*)(W2f + (size_t)u * 8) = w;
  }
}

// grid NIGRP*JSPLIT = 2048, block 64 (1 wave). Wave: i0..i0+2, 24 j-tiles
// in two half-runs of 12, order swapped by blockIdx parity (anti-phase).
__global__ __launch_bounds__(64, 2) void pairmlp_max_kernel(
    const _Float16* __restrict__ Qf, const _Float16* __restrict__ P,
    const _Float16* __restrict__ W2f, const float* __restrict__ b2,
    float* __restrict__ out)
{
  const int lane = threadIdx.x;
  const int quad = lane >> 4;
  const int lcol = lane & 15;
  const int ig = blockIdx.x % NIGRP;  // consecutive blocks: same js ->
  const int js = blockIdx.x / NIGRP;  // same Q tile stream (L1/L2 reuse)
  const int i0 = ig * NI;
  const int par = blockIdx.x & 1;     // stagger parity

  // B fragments from pre-fragmented W2f: 16 coalesced 16B loads
  half8 bfrag[4][4];
  {
    const half8* wf = (const half8*)W2f + lane;
    #pragma unroll
    for (int ct = 0; ct < 4; ++ct)
      #pragma unroll
      for (int ks = 0; ks < 4; ++ks)
        bfrag[ct][ks] = wf[(ct * 4 + ks) * 64];
  }

  // P fragments for NI i's
  half8 pv[NI][4];
  #pragma unroll
  for (int ii = 0; ii < NI; ++ii) {
    const _Float16* prow = P + (i0 + ii) * MM + quad * 8;
    #pragma unroll
    for (int ks = 0; ks < 4; ++ks)
      pv[ii][ks] = *(const half8*)(prow + ks * 32);
  }

  float b2v[4];
  #pragma unroll
  for (int ct = 0; ct < 4; ++ct) b2v[ct] = b2[ct * 16 + lcol];

  float rmax[NI][4];
  #pragma unroll
  for (int ii = 0; ii < NI; ++ii)
    #pragma unroll
    for (int ct = 0; ct < 4; ++ct) rmax[ii][ct] = -3.0e38f;

  // byte base: tile jt at jt*4096, ks at +1024*ks, lane at +16*lane
  const char* qbytes = (const char*)Qf + (size_t)(js * NTILE) * 4096 + lane * 16;

  const half8 hz = 0;

  // compute one 16-j tile held in qt[4] against all NI i's
  auto compute_tile = [&](const half8* qt) {
    f32x4 acc[NI][4];
    #pragma unroll
    for (int ks = 0; ks < 4; ++ks) {
      __builtin_amdgcn_s_setprio(1);
      #pragma unroll
      for (int ii = 0; ii < NI; ++ii) {
        half8 s = qt[ks] - pv[ii][ks];
        s = __builtin_elementwise_max(s, hz);
        #pragma unroll
        for (int ct = 0; ct < 4; ++ct) {
          if (ks == 0)
            acc[ii][ct] = __builtin_amdgcn_mfma_f32_16x16x32_f16(
                s, bfrag[ct][0], f32x4{0.f, 0.f, 0.f, 0.f}, 0, 0, 0);
          else
            acc[ii][ct] = __builtin_amdgcn_mfma_f32_16x16x32_f16(
                s, bfrag[ct][ks], acc[ii][ct], 0, 0, 0);
        }
      }
      __builtin_amdgcn_s_setprio(0);
    }
    // C/D: col=lcol+ct*16, row(j)=quad*4+reg. Raw max; +b2/relu deferred.
    #pragma unroll
    for (int ii = 0; ii < NI; ++ii)
      #pragma unroll
      for (int ct = 0; ct < 4; ++ct) {
        const float t3 = fmaxf(fmaxf(acc[ii][ct][0], acc[ii][ct][1]), acc[ii][ct][2]);
        rmax[ii][ct] = fmaxf(fmaxf(t3, acc[ii][ct][3]), rmax[ii][ct]);
      }
  };

  half8 qc[4], qn[4];

  // two half-runs of HTILE tiles; order swapped by parity (anti-phase stagger)
  for (int h = 0; h < 2; ++h) {
    const char* runb = qbytes + (((h ^ par) != 0) ? HTILE * 4096 : 0);
    const char* qp = runb;

    // prime qc from first tile of this run
    #pragma unroll
    for (int ks = 0; ks < 4; ++ks)
      qc[ks] = *(const half8*)(qp + ks * 1024);

    for (int t = 0; t < HTILE; t += 2) {
      // prefetch tile t+1 (imm offsets off qp+4096)
      #pragma unroll
      for (int ks = 0; ks < 4; ++ks)
        qn[ks] = *(const half8*)(qp + 4096 + ks * 1024);
      compute_tile(qc);  // tile t

      // prefetch tile t+2 (dummy run-start on last pair; unused)
      const char* q2 = (t + 2 < HTILE) ? (qp + 8192) : runb;
      #pragma unroll
      for (int ks = 0; ks < 4; ++ks)
        qc[ks] = *(const half8*)(q2 + ks * 1024);
      compute_tile(qn);  // tile t+1

      qp += 8192;
    }
  }

  // combine quad-groups (different j rows, same col), then atomic max.
  #pragma unroll
  for (int ii = 0; ii < NI; ++ii)
    #pragma unroll
    for (int ct = 0; ct < 4; ++ct) {
      float v = rmax[ii][ct];
      v = fmaxf(v, __shfl_xor(v, 16, 64));
      v = fmaxf(v, __shfl_xor(v, 32, 64));
      v = fmaxf(v + b2v[ct], 0.f);
      if (quad == 0)
        atomicMax((unsigned*)(out + (i0 + ii) * HH + ct * 16 + lcol), __float_as_uint(v));
    }
}

extern "C" void kernel_launch(void* const* d_in, const int* in_sizes, int n_in,
                              void* d_out, int out_size, void* d_ws, size_t ws_size,
                              hipStream_t stream) {
  const float* hidden = (const float*)d_in[0];
  const float* gt     = (const float*)d_in[1];
  const float* We     = (const float*)d_in[2];
  const float* be     = (const float*)d_in[3];
  const float* W1     = (const float*)d_in[4];
  const float* b1     = (const float*)d_in[5];
  const float* W2     = (const float*)d_in[6];
  const float* b2     = (const float*)d_in[7];
  float* out = (float*)d_out;

  _Float16* Qf  = (_Float16*)d_ws;     // NN*MM fp16 (384KB), frag-tile layout
  _Float16* Ph  = Qf + NN * MM;        // NN*MM fp16 (384KB)
  _Float16* W2f = Ph + NN * MM;        // 4*4*64*8 fp16 (16KB), frag layout

  precompute_kernel<<<NN, 128, 0, stream>>>(hidden, gt, We, be, W1, b1, W2, Qf, Ph, W2f, out);
  pairmlp_max_kernel<<<NIGRP * JSPLIT, 64, 0, stream>>>(Qf, Ph, W2f, b2, out);
}